// Round 6
// baseline (22980.244 us; speedup 1.0000x reference)
//
#include <hip/hip_runtime.h>
#include <hip/hip_bf16.h>

#define V 50257
#define D 128
#define TT 256
#define NSTEPS 5
#define EPSF 1e-10f

// ws layout (float offsets)
#define WS_M  0          // [9][128][128]  M = B B^T
#define WS_BT 147456     // [9][128][128]  BT[d][e] = B[e][d]
#define WS_U  294912     // [256][9][128]  normalized expr vectors per step
#define WS_Z  589824     // [256] softmax denominators

__device__ __forceinline__ float frcp(float x) { return __builtin_amdgcn_rcpf(x); }

__device__ __forceinline__ float wred(float v) {
  v += __shfl_xor(v, 1);  v += __shfl_xor(v, 2);  v += __shfl_xor(v, 4);
  v += __shfl_xor(v, 8);  v += __shfl_xor(v, 16); v += __shfl_xor(v, 32);
  return v;
}

// DPP wave64 sum: row_shr 1/2/4/8 -> row sums in lanes 15/31/47/63;
// bcast15 (rows 1,3) -> lane31 = r0+r1, lane63 = r2+r3; bcast31 (rows 2,3)
// -> lane63 = total. readlane(63) broadcasts as uniform.
template<int CTRL, int RM>
__device__ __forceinline__ float dpp_add(float x) {
  int v = __builtin_amdgcn_update_dpp(0, __builtin_bit_cast(int, x), CTRL, RM, 0xf, true);
  return x + __builtin_bit_cast(float, v);
}
__device__ __forceinline__ float wredsum(float x) {
  x = dpp_add<0x111, 0xf>(x);   // row_shr:1
  x = dpp_add<0x112, 0xf>(x);   // row_shr:2
  x = dpp_add<0x114, 0xf>(x);   // row_shr:4
  x = dpp_add<0x118, 0xf>(x);   // row_shr:8
  x = dpp_add<0x142, 0xa>(x);   // row_bcast15 -> rows 1,3
  x = dpp_add<0x143, 0xc>(x);   // row_bcast31 -> rows 2,3
  return __builtin_bit_cast(float, __builtin_amdgcn_readlane(__builtin_bit_cast(int, x), 63));
}

// ---------------- init: M = B B^T (fp32), BT = B^T ----------------
__global__ void foam_init(const float* __restrict__ Bg, float* __restrict__ ws)
{
  const int kn = blockIdx.x;     // 0..8
  const int part = blockIdx.y;   // 0..3
  const int tid = threadIdx.x;   // 256
  __shared__ float Bs[128][129];
  for (int idx = tid; idx < 16384; idx += 256) {
    int e = idx >> 7, d = idx & 127;
    Bs[e][d] = Bg[(size_t)kn * 16384 + idx];
  }
  __syncthreads();
  float* Mw = ws + WS_M  + (size_t)kn * 16384;
  float* Tw = ws + WS_BT + (size_t)kn * 16384;
  const int base = part * 4096;
  for (int idx = base + tid; idx < base + 4096; idx += 256) {
    int e = idx >> 7, f = idx & 127;
    float acc = 0.f;
    #pragma unroll 4
    for (int d = 0; d < 128; ++d) acc = fmaf(Bs[e][d], Bs[f][d], acc);
    Mw[idx] = acc;
    Tw[idx] = Bs[f][e];   // BT[d=e][col=f] = B[col][d]
  }
}

// ---------------- per-k equilibrate over all 256 steps ----------------
// 8 waves; lane = fg*16+dl; wave owns output rows down = wv*16+dl;
// Mreg[n][j] = M[n][down][fg*32+j] pinned in VGPRs via asm.
// All waves redundantly run the scalar chain (DPP dots); exprL double-
// buffered in LDS -> ONE barrier per equilibration iteration.
__global__ __attribute__((amdgpu_flat_work_group_size(512,512), amdgpu_waves_per_eu(2,2)))
void foam_equil(
  const int* __restrict__ tokens, const float* __restrict__ E,
  const float* __restrict__ tension, const float* __restrict__ temperature,
  const float* __restrict__ target_sim, const float* __restrict__ step_size,
  const float* __restrict__ anchor_logit, const float* __restrict__ mdbp,
  const float* __restrict__ sensp, float* __restrict__ ws)
{
  const int k    = blockIdx.x;
  const int tid  = threadIdx.x;
  const int lane = tid & 63;
  const int wv   = tid >> 6;        // 0..7
  const int fg   = lane >> 4;       // 0..3
  const int dl   = lane & 15;
  const int down = wv * 16 + dl;    // owned output row
  const int f0   = fg * 32;         // owned f-slice
  const int ochunk = dl >> 1;       // chunk jj holding this lane's fsum slots
  const int oq0    = 2 * (dl & 1);  // q offset within that chunk

  const float* Mw = ws + WS_M  + (size_t)(3 * k) * 16384;
  const float* Tw = ws + WS_BT + (size_t)(3 * k) * 16384;
  float* Uw = ws + WS_U;

  float Mreg[3][32];
  #pragma unroll
  for (int n = 0; n < 3; ++n) {
    const float* src = Mw + n * 16384 + (size_t)down * 128 + f0;
    #pragma unroll
    for (int j = 0; j < 32; ++j) Mreg[n][j] = src[j];
  }
  // pin M in VGPRs: opaque redefinition prevents load rematerialization
  #pragma unroll
  for (int n = 0; n < 3; ++n) {
    #pragma unroll
    for (int j = 0; j < 32; ++j) asm volatile("" : "+v"(Mreg[n][j]));
  }

  const float temp  = fmaxf(fabsf(temperature[k]), 0.01f);
  const float tgt   = target_sim[k];
  const float stp   = fminf(fmaxf(fabsf(step_size[k]), 0.001f), 0.5f);
  const float aw    = frcp(1.f + __expf(-anchor_logit[k]));
  const float mdbv  = mdbp[0];
  const float sensv = fabsf(sensp[0]);

  float inter[3][3];
  #pragma unroll
  for (int n = 0; n < 3; ++n) {
    float a0 = -tension[(k * 3 + n) * 3 + 0] / temp;
    float a1 = -tension[(k * 3 + n) * 3 + 1] / temp;
    float a2 = -tension[(k * 3 + n) * 3 + 2] / temp;
    float mx = fmaxf(a0, fmaxf(a1, a2));
    float s  = frcp(__expf(a0 - mx) + __expf(a1 - mx) + __expf(a2 - mx));
    inter[n][0] = __expf(a0 - mx) * s;
    inter[n][1] = __expf(a1 - mx) * s;
    inter[n][2] = __expf(a2 - mx) * s;
  }

  __shared__ __align__(16) float eL[2][3][128];   // double-buffered expr
  __shared__ __align__(16) float mmL[128];
  __shared__ __align__(16) float svL[3][128];

  if (tid < 128) mmL[tid] = 0.f;
  __syncthreads();

  for (int t = 0; t < TT; ++t) {
    const int tok = tokens[t];
    const float* er = E + (size_t)tok * 128;
    // -------- prologue (all waves, redundant) --------
    float xA = er[lane], xB = er[lane + 64];
    float mA = mmL[lane], mB = mmL[lane + 64];
    float pxx = wredsum(xA * xA + xB * xB);
    float pmm = wredsum(mA * mA + mB * mB);
    float pmx = wredsum(mA * xA + mB * xB);
    float xn   = sqrtf(pxx) + EPSF;
    float mmn  = sqrtf(pmm) + EPSF;
    float cosv = pmx * frcp(xn * mmn);
    float nov  = (mmn > 1e-8f) ? (1.f - cosv) : 1.f;
    float decay = frcp(1.f + __expf(-(mdbv - sensv * nov)));
    float xwA = xA + decay * mA, xwB = xB + decay * mB;
    float gxx = pxx + 2.f * decay * pmx + decay * decay * pmm;
    float anorm = sqrtf(gxx) + EPSF;

    float xwS[32];
    float xwOwn0 = 0.f, xwOwn1 = 0.f;
    float a0 = 0.f, a1 = 0.f, a2 = 0.f;
    {
      const float4* ef4 = reinterpret_cast<const float4*>(er + f0);
      #pragma unroll
      for (int jj = 0; jj < 8; ++jj) {
        float4 xq = ef4[jj];
        float4 mq = *reinterpret_cast<const float4*>(&mmL[f0 + 4 * jj]);
        float w0 = xq.x + decay * mq.x;
        float w1 = xq.y + decay * mq.y;
        float w2 = xq.z + decay * mq.z;
        float w3 = xq.w + decay * mq.w;
        xwS[4*jj] = w0; xwS[4*jj+1] = w1; xwS[4*jj+2] = w2; xwS[4*jj+3] = w3;
        a0 = fmaf(Mreg[0][4*jj], w0, fmaf(Mreg[0][4*jj+1], w1, fmaf(Mreg[0][4*jj+2], w2, fmaf(Mreg[0][4*jj+3], w3, a0))));
        a1 = fmaf(Mreg[1][4*jj], w0, fmaf(Mreg[1][4*jj+1], w1, fmaf(Mreg[1][4*jj+2], w2, fmaf(Mreg[1][4*jj+3], w3, a1))));
        a2 = fmaf(Mreg[2][4*jj], w0, fmaf(Mreg[2][4*jj+1], w1, fmaf(Mreg[2][4*jj+2], w2, fmaf(Mreg[2][4*jj+3], w3, a2))));
        if (jj == ochunk) {
          xwOwn0 = (oq0 == 0) ? w0 : w2;
          xwOwn1 = (oq0 == 0) ? w1 : w3;
        }
      }
    }
    a0 += __shfl_xor(a0, 16); a0 += __shfl_xor(a0, 32);
    a1 += __shfl_xor(a1, 16); a1 += __shfl_xor(a1, 32);
    a2 += __shfl_xor(a2, 16); a2 += __shfl_xor(a2, 32);
    float eD0 = a0, eD1 = a1, eD2 = a2;
    if (fg == 0) { eL[0][0][down] = eD0; eL[0][1][down] = eD1; eL[0][2][down] = eD2; }
    float fs00 = 0.f, fs01 = 0.f, fs10 = 0.f, fs11 = 0.f, fs20 = 0.f, fs21 = 0.f;
    __syncthreads();                       // B0

    // -------- 5 equilibration iterations, ONE barrier each --------
    #pragma unroll 1
    for (int it = 0; it < NSTEPS; ++it) {
      const int rb = it & 1;
      const float (*eb)[128] = eL[rb];
      float e0A = eb[0][lane], e0B = eb[0][lane + 64];
      float e1A = eb[1][lane], e1B = eb[1][lane + 64];
      float e2A = eb[2][lane], e2B = eb[2][lane + 64];
      float g0 = wredsum(e0A * e0A + e0B * e0B);
      float g1 = wredsum(e0A * e1A + e0B * e1B);
      float g2 = wredsum(e0A * e2A + e0B * e2B);
      float g3 = wredsum(e1A * e1A + e1B * e1B);
      float g4 = wredsum(e1A * e2A + e1B * e2B);
      float g5 = wredsum(e2A * e2A + e2B * e2B);
      float g6 = wredsum(e0A * xwA + e0B * xwB);
      float g7 = wredsum(e1A * xwA + e1B * xwB);
      float g8 = wredsum(e2A * xwA + e2B * xwB);

      float e0n = sqrtf(g0) + EPSF;
      float e1n = sqrtf(g3) + EPSF;
      float e2n = sqrtf(g5) + EPSF;
      float cq01 = g1 * frcp(e0n * e1n) - tgt;
      float cq02 = g2 * frcp(e0n * e2n) - tgt;
      float cq12 = g4 * frcp(e1n * e2n) - tgt;
      float rd01 = frcp(sqrtf(fmaxf(g0 + g3 - 2.f * g1, 0.f)) + EPSF);
      float rd02 = frcp(sqrtf(fmaxf(g0 + g5 - 2.f * g2, 0.f)) + EPSF);
      float rd12 = frcp(sqrtf(fmaxf(g3 + g5 - 2.f * g4, 0.f)) + EPSF);
      float w01 = cq01 * inter[0][1] * rd01, w10 = cq01 * inter[1][0] * rd01;
      float w02 = cq02 * inter[0][2] * rd02, w20 = cq02 * inter[2][0] * rd02;
      float w12 = cq12 * inter[1][2] * rd12, w21 = cq12 * inter[2][1] * rd12;
      float v0 = (g6 * frcp(e0n * anorm) - tgt) * aw * frcp(sqrtf(fmaxf(g0 + gxx - 2.f * g6, 0.f)) + EPSF);
      float v1 = (g7 * frcp(e1n * anorm) - tgt) * aw * frcp(sqrtf(fmaxf(g3 + gxx - 2.f * g7, 0.f)) + EPSF);
      float v2 = (g8 * frcp(e2n * anorm) - tgt) * aw * frcp(sqrtf(fmaxf(g5 + gxx - 2.f * g8, 0.f)) + EPSF);

      float m0 = 0.f, m1 = 0.f, m2 = 0.f;
      #pragma unroll
      for (int jj = 0; jj < 8; ++jj) {
        float4 q0 = *reinterpret_cast<const float4*>(&eb[0][f0 + 4 * jj]);
        float4 q1 = *reinterpret_cast<const float4*>(&eb[1][f0 + 4 * jj]);
        float4 q2 = *reinterpret_cast<const float4*>(&eb[2][f0 + 4 * jj]);
        #pragma unroll
        for (int q = 0; q < 4; ++q) {
          float b0 = (q == 0) ? q0.x : (q == 1) ? q0.y : (q == 2) ? q0.z : q0.w;
          float b1 = (q == 0) ? q1.x : (q == 1) ? q1.y : (q == 2) ? q1.z : q1.w;
          float b2 = (q == 0) ? q2.x : (q == 1) ? q2.y : (q == 2) ? q2.z : q2.w;
          float xq = xwS[4 * jj + q];
          float F0 = w01 * (b0 - b1) + w02 * (b0 - b2) + v0 * (b0 - xq);
          float F1 = w10 * (b1 - b0) + w12 * (b1 - b2) + v1 * (b1 - xq);
          float F2 = w20 * (b2 - b0) + w21 * (b2 - b1) + v2 * (b2 - xq);
          m0 = fmaf(Mreg[0][4 * jj + q], F0, m0);
          m1 = fmaf(Mreg[1][4 * jj + q], F1, m1);
          m2 = fmaf(Mreg[2][4 * jj + q], F2, m2);
          if (jj == ochunk && q == oq0)     { fs00 += F0; fs10 += F1; fs20 += F2; }
          if (jj == ochunk && q == oq0 + 1) { fs01 += F0; fs11 += F1; fs21 += F2; }
        }
      }
      m0 += __shfl_xor(m0, 16); m0 += __shfl_xor(m0, 32);
      m1 += __shfl_xor(m1, 16); m1 += __shfl_xor(m1, 32);
      m2 += __shfl_xor(m2, 16); m2 += __shfl_xor(m2, 32);
      eD0 += stp * m0; eD1 += stp * m1; eD2 += stp * m2;
      if (fg == 0) {
        eL[rb ^ 1][0][down] = eD0;
        eL[rb ^ 1][1][down] = eD1;
        eL[rb ^ 1][2][down] = eD2;
      }
      __syncthreads();                     // one barrier per iteration
    }

    // -------- epilogue: final e in eL[1] --------
    {
      float e0A = eL[1][0][lane], e0B = eL[1][0][lane + 64];
      float e1A = eL[1][1][lane], e1B = eL[1][1][lane + 64];
      float e2A = eL[1][2][lane], e2B = eL[1][2][lane + 64];
      float s0 = wredsum(e0A * e0A + e0B * e0B);
      float s1 = wredsum(e1A * e1A + e1B * e1B);
      float s2 = wredsum(e2A * e2A + e2B * e2B);
      if (wv == 0) {
        float r0 = frcp(sqrtf(s0) + EPSF);
        float r1 = frcp(sqrtf(s1) + EPSF);
        float r2 = frcp(sqrtf(s2) + EPSF);
        float* ub = Uw + (size_t)t * 1152 + k * 384;
        ub[lane]            = e0A * r0;  ub[lane + 64]       = e0B * r0;
        ub[128 + lane]      = e1A * r1;  ub[128 + lane + 64] = e1B * r1;
        ub[256 + lane]      = e2A * r2;  ub[256 + lane + 64] = e2B * r2;
        svL[0][f0 + 2 * dl]     = xwOwn0 + stp * fs00;
        svL[0][f0 + 2 * dl + 1] = xwOwn1 + stp * fs01;
        svL[1][f0 + 2 * dl]     = xwOwn0 + stp * fs10;
        svL[1][f0 + 2 * dl + 1] = xwOwn1 + stp * fs11;
        svL[2][f0 + 2 * dl]     = xwOwn0 + stp * fs20;
        svL[2][f0 + 2 * dl + 1] = xwOwn1 + stp * fs21;
      }
    }
    __syncthreads();                       // E1

    // mm update: mm = decay*mm + (1-decay) * (1/3) * sum_n (BT_n s_n)
    {
      float a = 0.f;
      #pragma unroll
      for (int n = 0; n < 3; ++n) {
        const float4* tp = reinterpret_cast<const float4*>(Tw + n * 16384 + (size_t)down * 128 + f0);
        #pragma unroll
        for (int jj = 0; jj < 8; ++jj) {
          float4 tv = tp[jj];
          float4 sv = *reinterpret_cast<const float4*>(&svL[n][f0 + 4 * jj]);
          a = fmaf(tv.x, sv.x, a); a = fmaf(tv.y, sv.y, a);
          a = fmaf(tv.z, sv.z, a); a = fmaf(tv.w, sv.w, a);
        }
      }
      a += __shfl_xor(a, 16); a += __shfl_xor(a, 32);
      if (fg == 0) mmL[down] = decay * mmL[down] + (1.f - decay) * (a * (1.f / 3.f));
    }
    __syncthreads();                       // E2
  }
}

// ---------------- spectral entropy per step (9x9 Gram + Jacobi) ----------------
__global__ void foam_entropy(const float* __restrict__ U, float* __restrict__ out)
{
  const int t = blockIdx.x;
  const int lane = threadIdx.x; // 64
  __shared__ float Us9[9][132];
  __shared__ float G[9][12];
  for (int idx = lane; idx < 1152; idx += 64)
    Us9[idx >> 7][idx & 127] = U[(size_t)t * 1152 + idx];
  __syncthreads();
  if (lane < 45) {
    int i = 0, rem = lane;
    while (rem >= 9 - i) { rem -= 9 - i; ++i; }
    int j = i + rem;
    float p = 0.f;
    for (int f = 0; f < 128; ++f) p = fmaf(Us9[i][f], Us9[j][f], p);
    p *= (1.f / 9.f);
    G[i][j] = p; G[j][i] = p;
  }
  __syncthreads();
  for (int sw = 0; sw < 8; ++sw) {
    for (int p = 0; p < 8; ++p) {
      for (int q = p + 1; q < 9; ++q) {
        float app = G[p][p], aqq = G[q][q], apq = G[p][q];
        bool doit = fabsf(apq) > 1e-20f;
        float c_ = 1.f, s_ = 0.f;
        if (doit) {
          float tau = (aqq - app) / (2.f * apq);
          float tsg = (tau >= 0.f) ? 1.f : -1.f;
          float tt = tsg / (fabsf(tau) + sqrtf(1.f + tau * tau));
          c_ = 1.f / sqrtf(1.f + tt * tt);
          s_ = tt * c_;
        }
        __syncthreads();
        if (doit) {
          if (lane < 9 && lane != p && lane != q) {
            float gp = G[p][lane], gq = G[q][lane];
            float np_ = c_ * gp - s_ * gq;
            float nq_ = s_ * gp + c_ * gq;
            G[p][lane] = np_; G[lane][p] = np_;
            G[q][lane] = nq_; G[lane][q] = nq_;
          }
          if (lane == 0) {
            float npp = c_ * c_ * app - 2.f * c_ * s_ * apq + s_ * s_ * aqq;
            float nqq = s_ * s_ * app + 2.f * c_ * s_ * apq + c_ * c_ * aqq;
            G[p][p] = npp; G[q][q] = nqq; G[p][q] = 0.f; G[q][p] = 0.f;
          }
        }
        __syncthreads();
      }
    }
  }
  if (lane == 0) {
    float tot = 119.f * 1e-12f;
    float lam[9];
    #pragma unroll
    for (int i = 0; i < 9; ++i) { lam[i] = fmaxf(G[i][i], 1e-12f); tot += lam[i]; }
    float S = 0.f;
    #pragma unroll
    for (int i = 0; i < 9; ++i) {
      float le = lam[i] / tot;
      S -= le * fmaxf(logf(le), -100.f);
    }
    float lz = 1e-12f / tot;
    S -= 119.f * (lz * fmaxf(logf(lz), -100.f));
    out[(size_t)TT * V + t] = S;
  }
}

// ---------------- logits: l[t,v] = (1/9) sum_i (E[v].u_i(t))^2 ----------------
__global__ __launch_bounds__(256, 2) void foam_logits(
  const float* __restrict__ E, const float* __restrict__ U, float* __restrict__ out)
{
  const int tid = threadIdx.x;
  const int v = blockIdx.x * 256 + tid;
  const bool valid = v < V;
  const int t0 = blockIdx.y * 32;
  float Er[128];
  {
    const float* erow = E + (size_t)(valid ? v : 0) * 128;
    #pragma unroll
    for (int j = 0; j < 128; j += 4) {
      float4 x = *reinterpret_cast<const float4*>(erow + j);
      Er[j] = x.x; Er[j + 1] = x.y; Er[j + 2] = x.z; Er[j + 3] = x.w;
    }
  }
  __shared__ __align__(16) float Us[1152];
  for (int t = t0; t < t0 + 32; ++t) {
    __syncthreads();
    for (int u2 = tid; u2 < 1152; u2 += 256) Us[u2] = U[(size_t)t * 1152 + u2];
    __syncthreads();
    float l = 0.f;
    for (int i = 0; i < 9; ++i) {
      float p = 0.f;
      #pragma unroll
      for (int j = 0; j < 128; j += 4) {
        const float4 uu = *reinterpret_cast<const float4*>(&Us[i * 128 + j]);
        p = fmaf(Er[j], uu.x, fmaf(Er[j + 1], uu.y, fmaf(Er[j + 2], uu.z, fmaf(Er[j + 3], uu.w, p))));
      }
      l = fmaf(p, p, l);
    }
    if (valid) out[(size_t)t * V + v] = l * (1.f / 9.f);
  }
}

// ---------------- softmax denom + H, F ----------------
__global__ __launch_bounds__(1024) void foam_zh(float* __restrict__ out, float* __restrict__ ws)
{
  const int t = blockIdx.x;
  const int tid = threadIdx.x;
  const float* lg = out + (size_t)t * V;
  float z = 0.f, w = 0.f;
  for (int v = tid; v < V; v += 1024) {
    float l = lg[v];
    float e = expf(l);
    z += e; w = fmaf(l, e, w);
  }
  z = wred(z); w = wred(w);
  __shared__ float zb[16], wb[16];
  if ((tid & 63) == 0) { zb[tid >> 6] = z; wb[tid >> 6] = w; }
  __syncthreads();
  if (tid == 0) {
    float Z = 0.f, W = 0.f;
    #pragma unroll
    for (int i = 0; i < 16; ++i) { Z += zb[i]; W += wb[i]; }
    ws[WS_Z + t] = Z;
    float H = logf(Z) - W / Z;
    out[(size_t)TT * V + TT + t] = H;
    out[(size_t)TT * V + 2 * TT + t] = H - out[(size_t)TT * V + t];
  }
}

// ---------------- probs in-place ----------------
__global__ __launch_bounds__(256) void foam_probs(float* __restrict__ out, const float* __restrict__ ws)
{
  const int t = blockIdx.y;
  const int v = blockIdx.x * 256 + threadIdx.x;
  if (v < V) {
    const float zi = 1.f / ws[WS_Z + t];
    float* p = out + (size_t)t * V;
    p[v] = expf(p[v]) * zi;
  }
}

extern "C" void kernel_launch(void* const* d_in, const int* in_sizes, int n_in,
                              void* d_out, int out_size, void* d_ws, size_t ws_size,
                              hipStream_t stream) {
  (void)in_sizes; (void)n_in; (void)out_size; (void)ws_size;
  const int*   tokens      = (const int*)d_in[0];
  const float* E           = (const float*)d_in[1];
  const float* bases       = (const float*)d_in[2];
  const float* tension     = (const float*)d_in[3];
  const float* temperature = (const float*)d_in[4];
  const float* target      = (const float*)d_in[5];
  const float* stepsz      = (const float*)d_in[6];
  const float* alogit      = (const float*)d_in[7];
  const float* mdb         = (const float*)d_in[8];
  const float* sens        = (const float*)d_in[9];
  float* out = (float*)d_out;
  float* ws  = (float*)d_ws;

  foam_init<<<dim3(9, 4), 256, 0, stream>>>(bases, ws);
  foam_equil<<<3, 512, 0, stream>>>(tokens, E, tension, temperature, target,
                                    stepsz, alogit, mdb, sens, ws);
  foam_entropy<<<256, 64, 0, stream>>>(ws + WS_U, out);
  foam_logits<<<dim3(197, 8), 256, 0, stream>>>(E, ws + WS_U, out);
  foam_zh<<<256, 1024, 0, stream>>>(out, ws);
  foam_probs<<<dim3(197, 256), 256, 0, stream>>>(out, ws);
}

// Round 7
// 5508.353 us; speedup vs baseline: 4.1719x; 4.1719x over previous
//
#include <hip/hip_runtime.h>
#include <hip/hip_bf16.h>

#define V 50257
#define D 128
#define TT 256
#define NSTEPS 5
#define EPSF 1e-10f

// ws layout (float offsets)
#define WS_M  0          // [9][128][128]  M = B B^T
#define WS_BT 147456     // [9][128][128]  BT[d][e] = B[e][d]
#define WS_U  294912     // [256][9][128]  normalized expr vectors per step
#define WS_Z  589824     // [256] softmax denominators

__device__ __forceinline__ float frcp(float x) { return __builtin_amdgcn_rcpf(x); }

__device__ __forceinline__ float wred(float v) {
  v += __shfl_xor(v, 1);  v += __shfl_xor(v, 2);  v += __shfl_xor(v, 4);
  v += __shfl_xor(v, 8);  v += __shfl_xor(v, 16); v += __shfl_xor(v, 32);
  return v;
}

// DPP wave64 sum (HW-verified in round 6: passed with absmax 0)
template<int CTRL, int RM>
__device__ __forceinline__ float dpp_add(float x) {
  int v = __builtin_amdgcn_update_dpp(0, __builtin_bit_cast(int, x), CTRL, RM, 0xf, true);
  return x + __builtin_bit_cast(float, v);
}
__device__ __forceinline__ float wredsum(float x) {
  x = dpp_add<0x111, 0xf>(x);   // row_shr:1
  x = dpp_add<0x112, 0xf>(x);   // row_shr:2
  x = dpp_add<0x114, 0xf>(x);   // row_shr:4
  x = dpp_add<0x118, 0xf>(x);   // row_shr:8
  x = dpp_add<0x142, 0xa>(x);   // row_bcast15 -> rows 1,3
  x = dpp_add<0x143, 0xc>(x);   // row_bcast31 -> rows 2,3
  return __builtin_bit_cast(float, __builtin_amdgcn_readlane(__builtin_bit_cast(int, x), 63));
}

// butterfly over 8-lane group (cg = lane&7): result uniform in group
__device__ __forceinline__ float bfly8(float v) {
  v += __shfl_xor(v, 1); v += __shfl_xor(v, 2); v += __shfl_xor(v, 4);
  return v;
}

// ---------------- init: M = B B^T (fp32), BT = B^T ----------------
__global__ void foam_init(const float* __restrict__ Bg, float* __restrict__ ws)
{
  const int kn = blockIdx.x;     // 0..8
  const int part = blockIdx.y;   // 0..3
  const int tid = threadIdx.x;   // 256
  __shared__ float Bs[128][129];
  for (int idx = tid; idx < 16384; idx += 256) {
    int e = idx >> 7, d = idx & 127;
    Bs[e][d] = Bg[(size_t)kn * 16384 + idx];
  }
  __syncthreads();
  float* Mw = ws + WS_M  + (size_t)kn * 16384;
  float* Tw = ws + WS_BT + (size_t)kn * 16384;
  const int base = part * 4096;
  for (int idx = base + tid; idx < base + 4096; idx += 256) {
    int e = idx >> 7, f = idx & 127;
    float acc = 0.f;
    #pragma unroll 4
    for (int d = 0; d < 128; ++d) acc = fmaf(Bs[e][d], Bs[f][d], acc);
    Mw[idx] = acc;
    Tw[idx] = Bs[f][e];   // BT[d=e][col=f] = B[col][d]
  }
}

// ---------------- per-k equilibrate over all 256 steps ----------------
// 1024 threads = 16 waves (4/SIMD for latency hiding).
// Matvec: row = wv*8 + rw owns M[n][row][cg*16 .. +16] -> 48 M floats/thread.
// Force dedupe: waves 0-5 (fn = wv>>1) compute F_fn for col fc = tid&127 once,
// write to fLb; per-wave only its own 6 gram dots + 3 coeffs. 12 barriers/token.
__global__ __launch_bounds__(1024, 1)
void foam_equil(
  const int* __restrict__ tokens, const float* __restrict__ E,
  const float* __restrict__ tension, const float* __restrict__ temperature,
  const float* __restrict__ target_sim, const float* __restrict__ step_size,
  const float* __restrict__ anchor_logit, const float* __restrict__ mdbp,
  const float* __restrict__ sensp, float* __restrict__ ws)
{
  const int k    = blockIdx.x;
  const int tid  = threadIdx.x;
  const int lane = tid & 63;
  const int wv   = tid >> 6;        // 0..15
  const int rw   = (lane >> 3) & 7; // 0..7
  const int cg   = lane & 7;        // 0..7
  const int row  = wv * 8 + rw;     // 0..127
  const int f0   = cg * 16;
  const int fn   = wv >> 1;         // F-matrix id for waves 0..5
  const int fc   = tid & 127;       // F col for waves 0..5

  const float* Mw = ws + WS_M  + (size_t)(3 * k) * 16384;
  const float* Tw = ws + WS_BT + (size_t)(3 * k) * 16384;
  float* Uw = ws + WS_U + k * 384;

  float Mreg[3][16];
  #pragma unroll
  for (int n = 0; n < 3; ++n) {
    const float* src = Mw + n * 16384 + (size_t)row * 128 + f0;
    #pragma unroll
    for (int j = 0; j < 16; ++j) Mreg[n][j] = src[j];
  }

  const float temp  = fmaxf(fabsf(temperature[k]), 0.01f);
  const float tgt   = target_sim[k];
  const float stp   = fminf(fmaxf(fabsf(step_size[k]), 0.001f), 0.5f);
  const float aw    = frcp(1.f + __expf(-anchor_logit[k]));
  const float mdbv  = mdbp[0];
  const float sensv = fabsf(sensp[0]);

  // partner indices + interaction weights for this wave's fn (waves 0-5)
  const int m1i = (fn + 1) % 3, m2i = (fn + 2) % 3;
  float inter_a = 0.f, inter_b = 0.f;
  if (wv < 6) {
    float a0 = -tension[(k * 3 + fn) * 3 + 0] / temp;
    float a1 = -tension[(k * 3 + fn) * 3 + 1] / temp;
    float a2 = -tension[(k * 3 + fn) * 3 + 2] / temp;
    float mx = fmaxf(a0, fmaxf(a1, a2));
    float s  = frcp(__expf(a0 - mx) + __expf(a1 - mx) + __expf(a2 - mx));
    float i0 = __expf(a0 - mx) * s, i1 = __expf(a1 - mx) * s, i2 = __expf(a2 - mx) * s;
    inter_a = (m1i == 0) ? i0 : (m1i == 1) ? i1 : i2;
    inter_b = (m2i == 0) ? i0 : (m2i == 1) ? i1 : i2;
  }

  __shared__ __align__(16) float xsL[2][128];
  __shared__ __align__(16) float mmL[128];
  __shared__ __align__(16) float eLb[2][3][128];
  __shared__ __align__(16) float fLb[3][128];
  __shared__ __align__(16) float svL[3][128];

  if (tid < 128) {
    mmL[tid] = 0.f;
    xsL[0][tid] = E[(size_t)tokens[0] * 128 + tid];
  }
  __syncthreads();

  for (int t = 0; t < TT; ++t) {
    const int cur = t & 1;
    // ---- P0: prefetch next x; decay chain; expr0 matvec ----
    float xnext = 0.f;
    {
      int tn = (t + 1 < TT) ? t + 1 : t;
      if (tid < 128) xnext = E[(size_t)tokens[tn] * 128 + tid];
    }
    float xA = xsL[cur][lane], xB = xsL[cur][lane + 64];
    float mA = mmL[lane],      mB = mmL[lane + 64];
    float pxx = wredsum(xA * xA + xB * xB);
    float pmm = wredsum(mA * mA + mB * mB);
    float pmx = wredsum(mA * xA + mB * xB);
    float xn   = sqrtf(pxx) + EPSF;
    float mmn  = sqrtf(pmm) + EPSF;
    float cosv = pmx * frcp(xn * mmn);
    float nov  = (mmn > 1e-8f) ? (1.f - cosv) : 1.f;
    const float decay = frcp(1.f + __expf(-(mdbv - sensv * nov)));
    const float xwA = xA + decay * mA, xwB = xB + decay * mB;
    const float gxx = pxx + 2.f * decay * pmx + decay * decay * pmm;
    const float anorm = sqrtf(gxx) + EPSF;

    float eD0, eD1, eD2;
    {
      float a0 = 0.f, a1 = 0.f, a2 = 0.f;
      #pragma unroll
      for (int jj = 0; jj < 4; ++jj) {
        float4 xq4 = *reinterpret_cast<const float4*>(&xsL[cur][f0 + 4 * jj]);
        float4 mq4 = *reinterpret_cast<const float4*>(&mmL[f0 + 4 * jj]);
        float w0 = xq4.x + decay * mq4.x;
        float w1 = xq4.y + decay * mq4.y;
        float w2 = xq4.z + decay * mq4.z;
        float w3 = xq4.w + decay * mq4.w;
        a0 = fmaf(Mreg[0][4*jj], w0, fmaf(Mreg[0][4*jj+1], w1, fmaf(Mreg[0][4*jj+2], w2, fmaf(Mreg[0][4*jj+3], w3, a0))));
        a1 = fmaf(Mreg[1][4*jj], w0, fmaf(Mreg[1][4*jj+1], w1, fmaf(Mreg[1][4*jj+2], w2, fmaf(Mreg[1][4*jj+3], w3, a1))));
        a2 = fmaf(Mreg[2][4*jj], w0, fmaf(Mreg[2][4*jj+1], w1, fmaf(Mreg[2][4*jj+2], w2, fmaf(Mreg[2][4*jj+3], w3, a2))));
      }
      eD0 = bfly8(a0); eD1 = bfly8(a1); eD2 = bfly8(a2);
      if (cg == 0) {
        eLb[0][0][row] = eD0; eLb[0][1][row] = eD1; eLb[0][2][row] = eD2;
      }
    }
    float fsv = 0.f;
    __syncthreads();                               // B0

    // ---- 5 equilibration iterations: Pa (F once) + Pb (matvec) ----
    #pragma unroll 1
    for (int it = 0; it < NSTEPS; ++it) {
      const int rb = it & 1;
      if (wv < 6) {
        const float (*eb)[128] = eLb[rb];
        float e0A = eb[0][lane], e0B = eb[0][lane + 64];
        float e1A = eb[1][lane], e1B = eb[1][lane + 64];
        float e2A = eb[2][lane], e2B = eb[2][lane + 64];
        float gd0 = wredsum(e0A * e0A + e0B * e0B);
        float gd1 = wredsum(e1A * e1A + e1B * e1B);
        float gd2 = wredsum(e2A * e2A + e2B * e2B);
        float eFA, eFB, eM1A, eM1B, eM2A, eM2B, gdF, gdM1, gdM2;
        if (fn == 0)      { eFA=e0A; eFB=e0B; eM1A=e1A; eM1B=e1B; eM2A=e2A; eM2B=e2B; gdF=gd0; gdM1=gd1; gdM2=gd2; }
        else if (fn == 1) { eFA=e1A; eFB=e1B; eM1A=e2A; eM1B=e2B; eM2A=e0A; eM2B=e0B; gdF=gd1; gdM1=gd2; gdM2=gd0; }
        else              { eFA=e2A; eFB=e2B; eM1A=e0A; eM1B=e0B; eM2A=e1A; eM2B=e1B; gdF=gd2; gdM1=gd0; gdM2=gd1; }
        float gc1 = wredsum(eFA * eM1A + eFB * eM1B);
        float gc2 = wredsum(eFA * eM2A + eFB * eM2B);
        float gax = wredsum(eFA * xwA + eFB * xwB);
        float enF  = sqrtf(gdF)  + EPSF;
        float enM1 = sqrtf(gdM1) + EPSF;
        float enM2 = sqrtf(gdM2) + EPSF;
        float cq1 = gc1 * frcp(enF * enM1) - tgt;
        float cq2 = gc2 * frcp(enF * enM2) - tgt;
        float rd1 = frcp(sqrtf(fmaxf(gdF + gdM1 - 2.f * gc1, 0.f)) + EPSF);
        float rd2 = frcp(sqrtf(fmaxf(gdF + gdM2 - 2.f * gc2, 0.f)) + EPSF);
        float wAc = cq1 * inter_a * rd1;
        float wBc = cq2 * inter_b * rd2;
        float vF  = (gax * frcp(enF * anorm) - tgt) * aw
                  * frcp(sqrtf(fmaxf(gdF + gxx - 2.f * gax, 0.f)) + EPSF);
        // F for this wave's (fn, fc) — computed once in the block
        float bF  = eb[fn][fc];
        float bM1 = eb[m1i][fc];
        float bM2 = eb[m2i][fc];
        float xq  = xsL[cur][fc] + decay * mmL[fc];
        float F = wAc * (bF - bM1) + wBc * (bF - bM2) + vF * (bF - xq);
        fsv += F;
        fLb[fn][fc] = F;
        if (it == NSTEPS - 1) svL[fn][fc] = xq + stp * fsv;
      }
      __syncthreads();                             // F ready

      // Pb: expr += stp * M * F   (all 16 waves)
      float a0 = 0.f, a1 = 0.f, a2 = 0.f;
      #pragma unroll
      for (int jj = 0; jj < 4; ++jj) {
        float4 q0 = *reinterpret_cast<const float4*>(&fLb[0][f0 + 4 * jj]);
        float4 q1 = *reinterpret_cast<const float4*>(&fLb[1][f0 + 4 * jj]);
        float4 q2 = *reinterpret_cast<const float4*>(&fLb[2][f0 + 4 * jj]);
        a0 = fmaf(Mreg[0][4*jj], q0.x, fmaf(Mreg[0][4*jj+1], q0.y, fmaf(Mreg[0][4*jj+2], q0.z, fmaf(Mreg[0][4*jj+3], q0.w, a0))));
        a1 = fmaf(Mreg[1][4*jj], q1.x, fmaf(Mreg[1][4*jj+1], q1.y, fmaf(Mreg[1][4*jj+2], q1.z, fmaf(Mreg[1][4*jj+3], q1.w, a1))));
        a2 = fmaf(Mreg[2][4*jj], q2.x, fmaf(Mreg[2][4*jj+1], q2.y, fmaf(Mreg[2][4*jj+2], q2.z, fmaf(Mreg[2][4*jj+3], q2.w, a2))));
      }
      eD0 += stp * bfly8(a0);
      eD1 += stp * bfly8(a1);
      eD2 += stp * bfly8(a2);
      if (cg == 0) {
        eLb[rb ^ 1][0][row] = eD0;
        eLb[rb ^ 1][1][row] = eD1;
        eLb[rb ^ 1][2][row] = eD2;
      }
      __syncthreads();                             // expr ready
    }

    // ---- Pe: U write (waves 0-2) + mm matvec (all) + x stash ----
    if (wv < 3) {
      float eA = eLb[1][wv][lane], eB = eLb[1][wv][lane + 64];
      float s = wredsum(eA * eA + eB * eB);
      float r = frcp(sqrtf(s) + EPSF);
      float* ub = Uw + (size_t)t * 1152 + wv * 128;
      ub[lane] = eA * r;  ub[lane + 64] = eB * r;
    }
    {
      float acc = 0.f;
      #pragma unroll
      for (int n = 0; n < 3; ++n) {
        const float4* tp = reinterpret_cast<const float4*>(Tw + n * 16384 + (size_t)row * 128 + f0);
        #pragma unroll
        for (int jj = 0; jj < 4; ++jj) {
          float4 tv = tp[jj];
          float4 sv = *reinterpret_cast<const float4*>(&svL[n][f0 + 4 * jj]);
          acc = fmaf(tv.x, sv.x, acc); acc = fmaf(tv.y, sv.y, acc);
          acc = fmaf(tv.z, sv.z, acc); acc = fmaf(tv.w, sv.w, acc);
        }
      }
      acc = bfly8(acc);
      if (cg == 0) mmL[row] = decay * mmL[row] + (1.f - decay) * (acc * (1.f / 3.f));
    }
    if (tid < 128) xsL[cur ^ 1][tid] = xnext;
    __syncthreads();                               // E2
  }
}

// ---------------- spectral entropy per step (9x9 Gram + Jacobi) ----------------
__global__ void foam_entropy(const float* __restrict__ U, float* __restrict__ out)
{
  const int t = blockIdx.x;
  const int lane = threadIdx.x; // 64
  __shared__ float Us9[9][132];
  __shared__ float G[9][12];
  for (int idx = lane; idx < 1152; idx += 64)
    Us9[idx >> 7][idx & 127] = U[(size_t)t * 1152 + idx];
  __syncthreads();
  if (lane < 45) {
    int i = 0, rem = lane;
    while (rem >= 9 - i) { rem -= 9 - i; ++i; }
    int j = i + rem;
    float p = 0.f;
    for (int f = 0; f < 128; ++f) p = fmaf(Us9[i][f], Us9[j][f], p);
    p *= (1.f / 9.f);
    G[i][j] = p; G[j][i] = p;
  }
  __syncthreads();
  for (int sw = 0; sw < 8; ++sw) {
    for (int p = 0; p < 8; ++p) {
      for (int q = p + 1; q < 9; ++q) {
        float app = G[p][p], aqq = G[q][q], apq = G[p][q];
        bool doit = fabsf(apq) > 1e-20f;
        float c_ = 1.f, s_ = 0.f;
        if (doit) {
          float tau = (aqq - app) / (2.f * apq);
          float tsg = (tau >= 0.f) ? 1.f : -1.f;
          float tt = tsg / (fabsf(tau) + sqrtf(1.f + tau * tau));
          c_ = 1.f / sqrtf(1.f + tt * tt);
          s_ = tt * c_;
        }
        __syncthreads();
        if (doit) {
          if (lane < 9 && lane != p && lane != q) {
            float gp = G[p][lane], gq = G[q][lane];
            float np_ = c_ * gp - s_ * gq;
            float nq_ = s_ * gp + c_ * gq;
            G[p][lane] = np_; G[lane][p] = np_;
            G[q][lane] = nq_; G[lane][q] = nq_;
          }
          if (lane == 0) {
            float npp = c_ * c_ * app - 2.f * c_ * s_ * apq + s_ * s_ * aqq;
            float nqq = s_ * s_ * app + 2.f * c_ * s_ * apq + c_ * c_ * aqq;
            G[p][p] = npp; G[q][q] = nqq; G[p][q] = 0.f; G[q][p] = 0.f;
          }
        }
        __syncthreads();
      }
    }
  }
  if (lane == 0) {
    float tot = 119.f * 1e-12f;
    float lam[9];
    #pragma unroll
    for (int i = 0; i < 9; ++i) { lam[i] = fmaxf(G[i][i], 1e-12f); tot += lam[i]; }
    float S = 0.f;
    #pragma unroll
    for (int i = 0; i < 9; ++i) {
      float le = lam[i] / tot;
      S -= le * fmaxf(logf(le), -100.f);
    }
    float lz = 1e-12f / tot;
    S -= 119.f * (lz * fmaxf(logf(lz), -100.f));
    out[(size_t)TT * V + t] = S;
  }
}

// ---------------- logits: l[t,v] = (1/9) sum_i (E[v].u_i(t))^2 ----------------
__global__ __launch_bounds__(256, 2) void foam_logits(
  const float* __restrict__ E, const float* __restrict__ U, float* __restrict__ out)
{
  const int tid = threadIdx.x;
  const int v = blockIdx.x * 256 + tid;
  const bool valid = v < V;
  const int t0 = blockIdx.y * 32;
  float Er[128];
  {
    const float* erow = E + (size_t)(valid ? v : 0) * 128;
    #pragma unroll
    for (int j = 0; j < 128; j += 4) {
      float4 x = *reinterpret_cast<const float4*>(erow + j);
      Er[j] = x.x; Er[j + 1] = x.y; Er[j + 2] = x.z; Er[j + 3] = x.w;
    }
  }
  __shared__ __align__(16) float Us[1152];
  for (int t = t0; t < t0 + 32; ++t) {
    __syncthreads();
    for (int u2 = tid; u2 < 1152; u2 += 256) Us[u2] = U[(size_t)t * 1152 + u2];
    __syncthreads();
    float l = 0.f;
    for (int i = 0; i < 9; ++i) {
      float p = 0.f;
      #pragma unroll
      for (int j = 0; j < 128; j += 4) {
        const float4 uu = *reinterpret_cast<const float4*>(&Us[i * 128 + j]);
        p = fmaf(Er[j], uu.x, fmaf(Er[j + 1], uu.y, fmaf(Er[j + 2], uu.z, fmaf(Er[j + 3], uu.w, p))));
      }
      l = fmaf(p, p, l);
    }
    if (valid) out[(size_t)t * V + v] = l * (1.f / 9.f);
  }
}

// ---------------- softmax denom + H, F ----------------
__global__ __launch_bounds__(1024) void foam_zh(float* __restrict__ out, float* __restrict__ ws)
{
  const int t = blockIdx.x;
  const int tid = threadIdx.x;
  const float* lg = out + (size_t)t * V;
  float z = 0.f, w = 0.f;
  for (int v = tid; v < V; v += 1024) {
    float l = lg[v];
    float e = expf(l);
    z += e; w = fmaf(l, e, w);
  }
  z = wred(z); w = wred(w);
  __shared__ float zb[16], wb[16];
  if ((tid & 63) == 0) { zb[tid >> 6] = z; wb[tid >> 6] = w; }
  __syncthreads();
  if (tid == 0) {
    float Z = 0.f, W = 0.f;
    #pragma unroll
    for (int i = 0; i < 16; ++i) { Z += zb[i]; W += wb[i]; }
    ws[WS_Z + t] = Z;
    float H = logf(Z) - W / Z;
    out[(size_t)TT * V + TT + t] = H;
    out[(size_t)TT * V + 2 * TT + t] = H - out[(size_t)TT * V + t];
  }
}

// ---------------- probs in-place ----------------
__global__ __launch_bounds__(256) void foam_probs(float* __restrict__ out, const float* __restrict__ ws)
{
  const int t = blockIdx.y;
  const int v = blockIdx.x * 256 + threadIdx.x;
  if (v < V) {
    const float zi = 1.f / ws[WS_Z + t];
    float* p = out + (size_t)t * V;
    p[v] = expf(p[v]) * zi;
  }
}

extern "C" void kernel_launch(void* const* d_in, const int* in_sizes, int n_in,
                              void* d_out, int out_size, void* d_ws, size_t ws_size,
                              hipStream_t stream) {
  (void)in_sizes; (void)n_in; (void)out_size; (void)ws_size;
  const int*   tokens      = (const int*)d_in[0];
  const float* E           = (const float*)d_in[1];
  const float* bases       = (const float*)d_in[2];
  const float* tension     = (const float*)d_in[3];
  const float* temperature = (const float*)d_in[4];
  const float* target      = (const float*)d_in[5];
  const float* stepsz      = (const float*)d_in[6];
  const float* alogit      = (const float*)d_in[7];
  const float* mdb         = (const float*)d_in[8];
  const float* sens        = (const float*)d_in[9];
  float* out = (float*)d_out;
  float* ws  = (float*)d_ws;

  foam_init<<<dim3(9, 4), 256, 0, stream>>>(bases, ws);
  foam_equil<<<3, 1024, 0, stream>>>(tokens, E, tension, temperature, target,
                                     stepsz, alogit, mdb, sens, ws);
  foam_entropy<<<256, 64, 0, stream>>>(ws + WS_U, out);
  foam_logits<<<dim3(197, 8), 256, 0, stream>>>(E, ws + WS_U, out);
  foam_zh<<<256, 1024, 0, stream>>>(out, ws);
  foam_probs<<<dim3(197, 256), 256, 0, stream>>>(out, ws);
}